// Round 1
// baseline (562.934 us; speedup 1.0000x reference)
//
#include <hip/hip_runtime.h>
#include <math.h>

#define N_PTS   8192
#define B_ROWS  4096

// ---------------------------------------------------------------------------
// Kernel 1: precompute per-point symmetric block W = M^T M, packed as 6 floats
//   M = [[sp(w0), w1, w2], [0, sp(w3), w4], [0, 0, sp(w5)]]
//   W00=a^2, W01=a*w1, W02=a*w2, W11=w1^2+d^2, W12=w1*w2+d*w4, W22=w2^2+w4^2+f^2
// ---------------------------------------------------------------------------
__device__ __forceinline__ float softplus_stable(float x) {
    // log(1+e^x) = max(x,0) + log1p(exp(-|x|))
    return fmaxf(x, 0.0f) + log1pf(__expf(-fabsf(x)) );
}

__global__ void prep_w_kernel(const float* __restrict__ weight,
                              float* __restrict__ wsym) {
    int n = blockIdx.x * blockDim.x + threadIdx.x;
    if (n >= N_PTS) return;
    const float* w = weight + n * 6;
    float w0 = w[0], w1 = w[1], w2 = w[2], w3 = w[3], w4 = w[4], w5 = w[5];
    float a = softplus_stable(w0);
    float d = softplus_stable(w3);
    float f = softplus_stable(w5);
    float* o = wsym + n * 6;
    o[0] = a * a;                                   // W00
    o[1] = a * w1;                                  // W01
    o[2] = a * w2;                                  // W02
    o[3] = fmaf(w1, w1, d * d);                     // W11
    o[4] = fmaf(w1, w2, d * w4);                    // W12
    o[5] = fmaf(w2, w2, fmaf(w4, w4, f * f));       // W22
}

// ---------------------------------------------------------------------------
// Kernel 2: one block per output row b.
//   out[b,j] = sum_n ( x0*W[n][0j] + x1*W[n][1j] + x2*W[n][2j] ) + 8192*bias[j]
// Each thread handles 8 segments of 4 triples (12 floats = 3x float4).
// W for 4 consecutive triples = 24 contiguous floats = 6x float4 (96B aligned).
// ---------------------------------------------------------------------------
__device__ __forceinline__ void triple_acc(float x0, float x1, float x2,
                                           float W00, float W01, float W02,
                                           float W11, float W12, float W22,
                                           float& a0, float& a1, float& a2) {
    a0 = fmaf(x0, W00, a0); a0 = fmaf(x1, W01, a0); a0 = fmaf(x2, W02, a0);
    a1 = fmaf(x0, W01, a1); a1 = fmaf(x1, W11, a1); a1 = fmaf(x2, W12, a1);
    a2 = fmaf(x0, W02, a2); a2 = fmaf(x1, W12, a2); a2 = fmaf(x2, W22, a2);
}

__global__ __launch_bounds__(256) void symm_main_kernel(
        const float* __restrict__ x,
        const float* __restrict__ wsym,
        const float* __restrict__ bias,
        float* __restrict__ out) {
    const int b = blockIdx.x;
    const int t = threadIdx.x;
    const float* row = x + (size_t)b * (N_PTS * 3);

    float a0 = 0.0f, a1 = 0.0f, a2 = 0.0f;

    // 8192 triples / 4 per segment = 2048 segments; 256 threads -> 8 iters.
    #pragma unroll 2
    for (int k = 0; k < 8; ++k) {
        const int s = t + k * 256;            // segment index (coalesced in t)
        const float4* xp = reinterpret_cast<const float4*>(row + 12 * s);
        const float4* wp = reinterpret_cast<const float4*>(wsym + 24 * s);
        float4 xa = xp[0];
        float4 xb = xp[1];
        float4 xc = xp[2];
        float4 wA = wp[0];
        float4 wB = wp[1];
        float4 wC = wp[2];
        float4 wD = wp[3];
        float4 wE = wp[4];
        float4 wF = wp[5];

        // triple 0: x=(xa.x,xa.y,xa.z)  W={wA.x,wA.y,wA.z,wA.w,wB.x,wB.y}
        triple_acc(xa.x, xa.y, xa.z, wA.x, wA.y, wA.z, wA.w, wB.x, wB.y, a0, a1, a2);
        // triple 1: x=(xa.w,xb.x,xb.y)  W={wB.z,wB.w,wC.x,wC.y,wC.z,wC.w}
        triple_acc(xa.w, xb.x, xb.y, wB.z, wB.w, wC.x, wC.y, wC.z, wC.w, a0, a1, a2);
        // triple 2: x=(xb.z,xb.w,xc.x)  W={wD.x,wD.y,wD.z,wD.w,wE.x,wE.y}
        triple_acc(xb.z, xb.w, xc.x, wD.x, wD.y, wD.z, wD.w, wE.x, wE.y, a0, a1, a2);
        // triple 3: x=(xc.y,xc.z,xc.w)  W={wE.z,wE.w,wF.x,wF.y,wF.z,wF.w}
        triple_acc(xc.y, xc.z, xc.w, wE.z, wE.w, wF.x, wF.y, wF.z, wF.w, a0, a1, a2);
    }

    // ---- block reduction: 256 threads -> 1, for 3 accumulators ----
    #pragma unroll
    for (int off = 32; off > 0; off >>= 1) {
        a0 += __shfl_down(a0, off, 64);
        a1 += __shfl_down(a1, off, 64);
        a2 += __shfl_down(a2, off, 64);
    }
    __shared__ float red[4][3];
    const int wave = t >> 6;
    const int lane = t & 63;
    if (lane == 0) {
        red[wave][0] = a0;
        red[wave][1] = a1;
        red[wave][2] = a2;
    }
    __syncthreads();
    if (t == 0) {
        float s0 = red[0][0] + red[1][0] + red[2][0] + red[3][0];
        float s1 = red[0][1] + red[1][1] + red[2][1] + red[3][1];
        float s2 = red[0][2] + red[1][2] + red[2][2] + red[3][2];
        const float nb = (float)N_PTS;
        out[b * 3 + 0] = fmaf(nb, bias[0], s0);
        out[b * 3 + 1] = fmaf(nb, bias[1], s1);
        out[b * 3 + 2] = fmaf(nb, bias[2], s2);
    }
}

// ---------------------------------------------------------------------------
extern "C" void kernel_launch(void* const* d_in, const int* in_sizes, int n_in,
                              void* d_out, int out_size, void* d_ws, size_t ws_size,
                              hipStream_t stream) {
    const float* input  = (const float*)d_in[0];   // [4096, 24576] f32
    const float* weight = (const float*)d_in[1];   // [8192, 6] f32
    const float* bias   = (const float*)d_in[2];   // [3] f32
    float* out  = (float*)d_out;                   // [4096, 3] f32
    float* wsym = (float*)d_ws;                    // 8192*6 f32 = 196608 B scratch

    prep_w_kernel<<<(N_PTS + 255) / 256, 256, 0, stream>>>(weight, wsym);
    symm_main_kernel<<<B_ROWS, 256, 0, stream>>>(input, wsym, bias, out);
}

// Round 2
// 521.220 us; speedup vs baseline: 1.0800x; 1.0800x over previous
//
#include <hip/hip_runtime.h>
#include <math.h>

#define N_PTS   8192
#define K_LEN   (N_PTS * 3)      // 24576 floats per row
#define B_ROWS  4096
#define RPB     4                // rows per block
#define NBLOCKS (B_ROWS / RPB)   // 1024
#define NITERS  (K_LEN / 4 / 256) // 24 float4-iters per thread

// ---------------------------------------------------------------------------
// Kernel 1: build three expanded weight vectors V0,V1,V2 (each K_LEN floats):
//   Vj[3n+i] = W_n(i,j), where W = M^T M (symmetric),
//   M = [[sp(w0), w1, w2], [0, sp(w3), w4], [0, 0, sp(w5)]]
// so that out[b,j] = dot(x[b,:], Vj) + N_PTS*bias[j].
// ---------------------------------------------------------------------------
__device__ __forceinline__ float softplus_stable(float x) {
    return fmaxf(x, 0.0f) + log1pf(__expf(-fabsf(x)));
}

__global__ void prep_v_kernel(const float* __restrict__ weight,
                              float* __restrict__ V) {
    int n = blockIdx.x * blockDim.x + threadIdx.x;
    if (n >= N_PTS) return;
    const float* w = weight + n * 6;
    float w0 = w[0], w1 = w[1], w2 = w[2], w3 = w[3], w4 = w[4], w5 = w[5];
    float a = softplus_stable(w0);
    float d = softplus_stable(w3);
    float f = softplus_stable(w5);
    float W00 = a * a;
    float W01 = a * w1;
    float W02 = a * w2;
    float W11 = fmaf(w1, w1, d * d);
    float W12 = fmaf(w1, w2, d * w4);
    float W22 = fmaf(w2, w2, fmaf(w4, w4, f * f));
    float* V0 = V;
    float* V1 = V + K_LEN;
    float* V2 = V + 2 * K_LEN;
    int k = 3 * n;
    V0[k] = W00; V0[k + 1] = W01; V0[k + 2] = W02;
    V1[k] = W01; V1[k + 1] = W11; V1[k + 2] = W12;
    V2[k] = W02; V2[k + 1] = W12; V2[k + 2] = W22;
}

// ---------------------------------------------------------------------------
// Kernel 2: 4 rows per block; all loads lane-contiguous float4.
// ---------------------------------------------------------------------------
__device__ __forceinline__ void dot4_acc(const float4& xv, const float4& v,
                                         float& a) {
    a = fmaf(xv.x, v.x, a);
    a = fmaf(xv.y, v.y, a);
    a = fmaf(xv.z, v.z, a);
    a = fmaf(xv.w, v.w, a);
}

__global__ __launch_bounds__(256) void symm_main_kernel(
        const float* __restrict__ x,
        const float* __restrict__ V,
        const float* __restrict__ bias,
        float* __restrict__ out) {
    const int b0 = blockIdx.x * RPB;
    const int t  = threadIdx.x;

    const float4* __restrict__ V0 = reinterpret_cast<const float4*>(V);
    const float4* __restrict__ V1 = reinterpret_cast<const float4*>(V + K_LEN);
    const float4* __restrict__ V2 = reinterpret_cast<const float4*>(V + 2 * K_LEN);
    const float4* __restrict__ xr0 = reinterpret_cast<const float4*>(x + (size_t)(b0 + 0) * K_LEN);
    const float4* __restrict__ xr1 = reinterpret_cast<const float4*>(x + (size_t)(b0 + 1) * K_LEN);
    const float4* __restrict__ xr2 = reinterpret_cast<const float4*>(x + (size_t)(b0 + 2) * K_LEN);
    const float4* __restrict__ xr3 = reinterpret_cast<const float4*>(x + (size_t)(b0 + 3) * K_LEN);

    float acc[RPB][3];
    #pragma unroll
    for (int r = 0; r < RPB; ++r)
        #pragma unroll
        for (int j = 0; j < 3; ++j)
            acc[r][j] = 0.0f;

    #pragma unroll 2
    for (int it = 0; it < NITERS; ++it) {
        const int idx = t + it * 256;
        float4 v0 = V0[idx];
        float4 v1 = V1[idx];
        float4 v2 = V2[idx];
        float4 xa = xr0[idx];
        float4 xb = xr1[idx];
        float4 xc = xr2[idx];
        float4 xd = xr3[idx];
        dot4_acc(xa, v0, acc[0][0]); dot4_acc(xa, v1, acc[0][1]); dot4_acc(xa, v2, acc[0][2]);
        dot4_acc(xb, v0, acc[1][0]); dot4_acc(xb, v1, acc[1][1]); dot4_acc(xb, v2, acc[1][2]);
        dot4_acc(xc, v0, acc[2][0]); dot4_acc(xc, v1, acc[2][1]); dot4_acc(xc, v2, acc[2][2]);
        dot4_acc(xd, v0, acc[3][0]); dot4_acc(xd, v1, acc[3][1]); dot4_acc(xd, v2, acc[3][2]);
    }

    // ---- reduce 12 accumulators: wave shuffle, then tiny LDS combine ----
    #pragma unroll
    for (int off = 32; off > 0; off >>= 1) {
        #pragma unroll
        for (int r = 0; r < RPB; ++r)
            #pragma unroll
            for (int j = 0; j < 3; ++j)
                acc[r][j] += __shfl_down(acc[r][j], off, 64);
    }

    __shared__ float red[4][RPB * 3];
    const int wave = t >> 6;
    const int lane = t & 63;
    if (lane == 0) {
        #pragma unroll
        for (int r = 0; r < RPB; ++r)
            #pragma unroll
            for (int j = 0; j < 3; ++j)
                red[wave][r * 3 + j] = acc[r][j];
    }
    __syncthreads();
    if (t < RPB * 3) {
        float s = red[0][t] + red[1][t] + red[2][t] + red[3][t];
        const int r = t / 3;
        const int j = t % 3;
        out[(b0 + r) * 3 + j] = fmaf((float)N_PTS, bias[j], s);
    }
}

// ---------------------------------------------------------------------------
extern "C" void kernel_launch(void* const* d_in, const int* in_sizes, int n_in,
                              void* d_out, int out_size, void* d_ws, size_t ws_size,
                              hipStream_t stream) {
    const float* input  = (const float*)d_in[0];   // [4096, 24576] f32
    const float* weight = (const float*)d_in[1];   // [8192, 6] f32
    const float* bias   = (const float*)d_in[2];   // [3] f32
    float* out = (float*)d_out;                    // [4096, 3] f32
    float* V   = (float*)d_ws;                     // 3 * 24576 f32 = 294912 B

    prep_v_kernel<<<N_PTS / 256, 256, 0, stream>>>(weight, V);
    symm_main_kernel<<<NBLOCKS, 256, 0, stream>>>(input, V, bias, out);
}

// Round 4
// 490.739 us; speedup vs baseline: 1.1471x; 1.0621x over previous
//
#include <hip/hip_runtime.h>
#include <math.h>

#define N_PTS   8192
#define K_LEN   (N_PTS * 3)        // 24576 floats per row
#define KV4     (K_LEN / 4)        // 6144 float4 per row
#define B_ROWS  4096
#define RPB     4                  // rows per block
#define NBLOCKS (B_ROWS / RPB)     // 1024
#define NITERS  (KV4 / 512)        // 12 iters: 2 float4 per row per thread per iter

typedef float v4f __attribute__((ext_vector_type(4)));

// ---------------------------------------------------------------------------
// Kernel 1: build three expanded weight vectors V0,V1,V2 (each K_LEN floats):
//   Vj[3n+i] = W_n(i,j), W = M^T M (symmetric),
//   M = [[sp(w0), w1, w2], [0, sp(w3), w4], [0, 0, sp(w5)]]
// out[b,j] = dot(x[b,:], Vj) + N_PTS*bias[j].
// ---------------------------------------------------------------------------
__device__ __forceinline__ float softplus_stable(float x) {
    return fmaxf(x, 0.0f) + log1pf(__expf(-fabsf(x)));
}

__global__ void prep_v_kernel(const float* __restrict__ weight,
                              float* __restrict__ V) {
    int n = blockIdx.x * blockDim.x + threadIdx.x;
    if (n >= N_PTS) return;
    const float* w = weight + n * 6;
    float w0 = w[0], w1 = w[1], w2 = w[2], w3 = w[3], w4 = w[4], w5 = w[5];
    float a = softplus_stable(w0);
    float d = softplus_stable(w3);
    float f = softplus_stable(w5);
    float W00 = a * a;
    float W01 = a * w1;
    float W02 = a * w2;
    float W11 = fmaf(w1, w1, d * d);
    float W12 = fmaf(w1, w2, d * w4);
    float W22 = fmaf(w2, w2, fmaf(w4, w4, f * f));
    float* V0 = V;
    float* V1 = V + K_LEN;
    float* V2 = V + 2 * K_LEN;
    int k = 3 * n;
    V0[k] = W00; V0[k + 1] = W01; V0[k + 2] = W02;
    V1[k] = W01; V1[k + 1] = W11; V1[k + 2] = W12;
    V2[k] = W02; V2[k + 1] = W12; V2[k + 2] = W22;
}

// ---------------------------------------------------------------------------
// Kernel 2: 4 rows per block; x loads non-temporal (stream-once), V cached.
// Per iter each thread handles 2 wave-contiguous float4 batches per row.
// ---------------------------------------------------------------------------
__device__ __forceinline__ void dot4_acc(const v4f& xv, const v4f& v, float& a) {
    a = fmaf(xv.x, v.x, a);
    a = fmaf(xv.y, v.y, a);
    a = fmaf(xv.z, v.z, a);
    a = fmaf(xv.w, v.w, a);
}

__global__ __launch_bounds__(256) void symm_main_kernel(
        const float* __restrict__ x,
        const float* __restrict__ V,
        const float* __restrict__ bias,
        float* __restrict__ out) {
    const int b0 = blockIdx.x * RPB;
    const int t  = threadIdx.x;

    const v4f* __restrict__ V0 = reinterpret_cast<const v4f*>(V);
    const v4f* __restrict__ V1 = reinterpret_cast<const v4f*>(V + K_LEN);
    const v4f* __restrict__ V2 = reinterpret_cast<const v4f*>(V + 2 * K_LEN);
    const v4f* __restrict__ xr0 = reinterpret_cast<const v4f*>(x + (size_t)(b0 + 0) * K_LEN);
    const v4f* __restrict__ xr1 = reinterpret_cast<const v4f*>(x + (size_t)(b0 + 1) * K_LEN);
    const v4f* __restrict__ xr2 = reinterpret_cast<const v4f*>(x + (size_t)(b0 + 2) * K_LEN);
    const v4f* __restrict__ xr3 = reinterpret_cast<const v4f*>(x + (size_t)(b0 + 3) * K_LEN);

    float acc[RPB][3];
    #pragma unroll
    for (int r = 0; r < RPB; ++r)
        #pragma unroll
        for (int j = 0; j < 3; ++j)
            acc[r][j] = 0.0f;

    for (int it = 0; it < NITERS; ++it) {
        const int i0 = t + it * 512;
        const int i1 = i0 + 256;
        // batch all 14 loads up front for max bytes-in-flight
        v4f va0 = V0[i0], va1 = V1[i0], va2 = V2[i0];
        v4f vb0 = V0[i1], vb1 = V1[i1], vb2 = V2[i1];
        v4f xa0 = __builtin_nontemporal_load(xr0 + i0);
        v4f xb0 = __builtin_nontemporal_load(xr0 + i1);
        v4f xa1 = __builtin_nontemporal_load(xr1 + i0);
        v4f xb1 = __builtin_nontemporal_load(xr1 + i1);
        v4f xa2 = __builtin_nontemporal_load(xr2 + i0);
        v4f xb2 = __builtin_nontemporal_load(xr2 + i1);
        v4f xa3 = __builtin_nontemporal_load(xr3 + i0);
        v4f xb3 = __builtin_nontemporal_load(xr3 + i1);

        dot4_acc(xa0, va0, acc[0][0]); dot4_acc(xa0, va1, acc[0][1]); dot4_acc(xa0, va2, acc[0][2]);
        dot4_acc(xb0, vb0, acc[0][0]); dot4_acc(xb0, vb1, acc[0][1]); dot4_acc(xb0, vb2, acc[0][2]);
        dot4_acc(xa1, va0, acc[1][0]); dot4_acc(xa1, va1, acc[1][1]); dot4_acc(xa1, va2, acc[1][2]);
        dot4_acc(xb1, vb0, acc[1][0]); dot4_acc(xb1, vb1, acc[1][1]); dot4_acc(xb1, vb2, acc[1][2]);
        dot4_acc(xa2, va0, acc[2][0]); dot4_acc(xa2, va1, acc[2][1]); dot4_acc(xa2, va2, acc[2][2]);
        dot4_acc(xb2, vb0, acc[2][0]); dot4_acc(xb2, vb1, acc[2][1]); dot4_acc(xb2, vb2, acc[2][2]);
        dot4_acc(xa3, va0, acc[3][0]); dot4_acc(xa3, va1, acc[3][1]); dot4_acc(xa3, va2, acc[3][2]);
        dot4_acc(xb3, vb0, acc[3][0]); dot4_acc(xb3, vb1, acc[3][1]); dot4_acc(xb3, vb2, acc[3][2]);
    }

    // ---- reduce 12 accumulators: wave shuffle, then tiny LDS combine ----
    #pragma unroll
    for (int off = 32; off > 0; off >>= 1) {
        #pragma unroll
        for (int r = 0; r < RPB; ++r)
            #pragma unroll
            for (int j = 0; j < 3; ++j)
                acc[r][j] += __shfl_down(acc[r][j], off, 64);
    }

    __shared__ float red[4][RPB * 3];
    const int wave = t >> 6;
    const int lane = t & 63;
    if (lane == 0) {
        #pragma unroll
        for (int r = 0; r < RPB; ++r)
            #pragma unroll
            for (int j = 0; j < 3; ++j)
                red[wave][r * 3 + j] = acc[r][j];
    }
    __syncthreads();
    if (t < RPB * 3) {
        float s = red[0][t] + red[1][t] + red[2][t] + red[3][t];
        const int r = t / 3;
        const int j = t % 3;
        out[(b0 + r) * 3 + j] = fmaf((float)N_PTS, bias[j], s);
    }
}

// ---------------------------------------------------------------------------
extern "C" void kernel_launch(void* const* d_in, const int* in_sizes, int n_in,
                              void* d_out, int out_size, void* d_ws, size_t ws_size,
                              hipStream_t stream) {
    const float* input  = (const float*)d_in[0];   // [4096, 24576] f32
    const float* weight = (const float*)d_in[1];   // [8192, 6] f32
    const float* bias   = (const float*)d_in[2];   // [3] f32
    float* out = (float*)d_out;                    // [4096, 3] f32
    float* V   = (float*)d_ws;                     // 3 * 24576 f32 = 294912 B

    prep_v_kernel<<<N_PTS / 256, 256, 0, stream>>>(weight, V);
    symm_main_kernel<<<NBLOCKS, 256, 0, stream>>>(input, V, bias, out);
}